// Round 4
// baseline (85.265 us; speedup 1.0000x reference)
//
#include <hip/hip_runtime.h>
#include <stdint.h>

// Problem constants
#define MDIM 8192   // batch
#define KDIM 512    // input size
#define TDIM 2080   // tril param count (64*65/2)
#define NPAD 2176   // TDIM padded to multiple of 128 (17*128)
#define MSZ  64     // matrix size

// 8-phase GEMM geometry
#define BM 256
#define BN 128
#define BK 64
#define BUF_ELEMS 24576   // (256*64 + 128*64) bf16 per buffer
#define BOFF      16384   // B region offset within buffer (elems)

typedef __attribute__((ext_vector_type(8))) __bf16 bf16x8;
typedef __attribute__((ext_vector_type(4))) float  f32x4;

__device__ __forceinline__ unsigned short f2bf(float f) {
    unsigned int u = __float_as_uint(f);
    u += 0x7fffu + ((u >> 16) & 1u);   // round-to-nearest-even
    return (unsigned short)(u >> 16);
}

// tril row index from linear tril index n
__device__ __forceinline__ int tril_row(int n) {
    int i = (int)((sqrtf((float)(8 * n + 1)) - 1.0f) * 0.5f);
    while ((i + 1) * (i + 2) / 2 <= n) ++i;
    while (i * (i + 1) / 2 > n) --i;
    return i;
}

// ---------------- fused convert kernel (x, W, bias/diag tables) ----------------
#define NX4 (MDIM * KDIM / 4)        // 1048576 float4 chunks of x
#define NW4 (NPAD * KDIM / 4)        // 278528 float4 chunks of padded W
#define NT4 (NPAD / 4)               // 544 table chunks

__global__ __launch_bounds__(256) void convert_kernel(const float* __restrict__ x,
                                                      const float* __restrict__ W,
                                                      const float* __restrict__ b,
                                                      unsigned short* __restrict__ xb,
                                                      unsigned short* __restrict__ wb,
                                                      float* __restrict__ biasf,
                                                      float* __restrict__ diagm) {
    int idx = blockIdx.x * 256 + threadIdx.x;
    if (idx < NX4) {
        float4 v = reinterpret_cast<const float4*>(x)[idx];
        reinterpret_cast<ushort4*>(xb)[idx] =
            make_ushort4(f2bf(v.x), f2bf(v.y), f2bf(v.z), f2bf(v.w));
    } else if (idx < NX4 + NW4) {
        int j = idx - NX4;
        int n = (j * 4) >> 9;                            // W row (KDIM=512)
        ushort4 o = make_ushort4(0, 0, 0, 0);
        if (n < TDIM) {
            float4 v = reinterpret_cast<const float4*>(W)[j];
            o = make_ushort4(f2bf(v.x), f2bf(v.y), f2bf(v.z), f2bf(v.w));
        }
        reinterpret_cast<ushort4*>(wb)[j] = o;
    } else {
        int t = idx - NX4 - NW4;
        if (t < NT4) {
#pragma unroll
            for (int r = 0; r < 4; ++r) {
                int n = t * 4 + r;
                float bv = 0.f, dm = 0.f;
                if (n < TDIM) {
                    bv = b[n];
                    int i = tril_row(n);
                    dm = (n - i * (i + 1) / 2 == i) ? 1.f : 0.f;
                }
                biasf[n] = bv;
                diagm[n] = dm;
            }
        }
    }
}

// ---------------- shared helpers ----------------
typedef __attribute__((address_space(1))) void as1_void;
typedef __attribute__((address_space(3))) void as3_void;

__device__ __forceinline__ void gload_lds16(const void* g, void* l) {
    // 16B direct global->LDS; dest is wave-uniform base + lane*16
    __builtin_amdgcn_global_load_lds((as1_void*)(void*)g, (as3_void*)l, 16, 0, 0);
}

// LDS tiles are [rows][64] bf16 (128B rows), XOR-swizzled: byte ^= (row&7)<<4
__device__ __forceinline__ bf16x8 frag_load(const unsigned short* base, int row, int kbyte) {
    kbyte ^= (row & 7) << 4;
    return *reinterpret_cast<const bf16x8*>(reinterpret_cast<const char*>(base) + row * 128 + kbyte);
}

// ---------------- GEMM1 (8-phase): chol = x @ W^T + b, diag-ReLU, bf16 ----------------
// BM=256 x BN=128, BK=64, 8 waves (4M x 2N), per-wave 64x64 = acc[4][4].
// 3-buffer LDS (144KB), depth-2 prefetch, counted vmcnt(6) per K-tile (T3+T4),
// setprio around MFMA clusters (T5), st-swizzle on LDS rows (T2).
__global__ __launch_bounds__(512, 1) void gemm8_kernel(const unsigned short* __restrict__ xb,
                                                       const unsigned short* __restrict__ wb,
                                                       const float* __restrict__ biasf,
                                                       const float* __restrict__ diagm,
                                                       unsigned short* __restrict__ chol) {
    __shared__ __align__(16) unsigned short S[3 * BUF_ELEMS];   // 144 KB
    const int tid  = threadIdx.x;
    const int lane = tid & 63;
    const int wave = tid >> 6;

    // XCD-aware decode: 544 = 8 XCDs x 68; XCD x owns mt in [4x, 4x+4), nt fastest.
    const int bid = blockIdx.x;
    const int xcd = bid & 7;
    const int c   = bid >> 3;            // 0..67
    const int mt  = xcd * 4 + c / 17;
    const int nt  = c % 17;
    const int m0 = mt * BM;
    const int n0 = nt * BN;

    const int wr = wave >> 1;            // 0..3 -> m offset
    const int wc = wave & 1;             // 0..1 -> n offset
    const int wm = wr * 64;
    const int wn = wc * 64;
    const int lr = lane & 15;
    const int lq = lane >> 4;

    // staging precompute
    const int rS = tid >> 3;                       // row-within-64-row op
    const unsigned short* gA = xb + (size_t)m0 * KDIM;
    const unsigned short* gB = wb + (size_t)n0 * KDIM;
    const int waveOff = (tid & 448) * 8;           // wave-uniform dest offset (elems)

#define STAGE_A(KT, A)                                                              \
    {                                                                               \
        int row = (A) * 64 + rS;                                                    \
        int ch  = (tid & 7) ^ (row & 7);                                            \
        gload_lds16(gA + (size_t)row * KDIM + (KT) * BK + ch * 8,                   \
                    &S[((KT) % 3) * BUF_ELEMS + (A) * 4096 + waveOff]);             \
    }
#define STAGE_B(KT, B)                                                              \
    {                                                                               \
        int row = (B) * 64 + rS;                                                    \
        int ch  = (tid & 7) ^ (row & 7);                                            \
        gload_lds16(gB + (size_t)row * KDIM + (KT) * BK + ch * 8,                   \
                    &S[((KT) % 3) * BUF_ELEMS + BOFF + (B) * 4096 + waveOff]);      \
    }

    f32x4 acc[4][4];
    f32x4 zero = {0.f, 0.f, 0.f, 0.f};
#pragma unroll
    for (int i = 0; i < 4; ++i)
#pragma unroll
        for (int j = 0; j < 4; ++j) acc[i][j] = zero;

    // prologue: stage kt=0 and kt=1 (6 ops each, FIFO order)
    STAGE_A(0, 0) STAGE_A(0, 1) STAGE_A(0, 2) STAGE_A(0, 3) STAGE_B(0, 0) STAGE_B(0, 1)
    STAGE_A(1, 0) STAGE_A(1, 1) STAGE_A(1, 2) STAGE_A(1, 3) STAGE_B(1, 0) STAGE_B(1, 1)
    asm volatile("s_waitcnt vmcnt(6)" ::: "memory");   // kt=0 complete (6 of kt=1 may fly)
    __builtin_amdgcn_s_barrier();

#pragma unroll
    for (int kt = 0; kt < 8; ++kt) {
        const unsigned short* Ab = &S[(kt % 3) * BUF_ELEMS];
        const unsigned short* Bb = Ab + BOFF;
#pragma unroll
        for (int p = 0; p < 4; ++p) {
            const int mq = (p >> 1) * 2;   // 0 or 2
            const int nq = (p & 1) * 2;    // 0 or 2
            // ds-read this quadrant's fragments
            bf16x8 a00 = frag_load(Ab, wm + (mq + 0) * 16 + lr, 0 * 64 + lq * 16);
            bf16x8 a01 = frag_load(Ab, wm + (mq + 0) * 16 + lr, 1 * 64 + lq * 16);
            bf16x8 a10 = frag_load(Ab, wm + (mq + 1) * 16 + lr, 0 * 64 + lq * 16);
            bf16x8 a11 = frag_load(Ab, wm + (mq + 1) * 16 + lr, 1 * 64 + lq * 16);
            bf16x8 b00 = frag_load(Bb, wn + (nq + 0) * 16 + lr, 0 * 64 + lq * 16);
            bf16x8 b01 = frag_load(Bb, wn + (nq + 0) * 16 + lr, 1 * 64 + lq * 16);
            bf16x8 b10 = frag_load(Bb, wn + (nq + 1) * 16 + lr, 0 * 64 + lq * 16);
            bf16x8 b11 = frag_load(Bb, wn + (nq + 1) * 16 + lr, 1 * 64 + lq * 16);
            // depth-2 prefetch: issue kt+2's 6 loads spread {2,2,1,1}
            if (kt < 6) {
                if (p == 0)      { STAGE_A(kt + 2, 0) STAGE_A(kt + 2, 1) }
                else if (p == 1) { STAGE_A(kt + 2, 2) STAGE_A(kt + 2, 3) }
                else if (p == 2) { STAGE_B(kt + 2, 0) }
                else             { STAGE_B(kt + 2, 1) }
            }
            __builtin_amdgcn_s_barrier();
            asm volatile("s_waitcnt lgkmcnt(0)" ::: "memory");
            __builtin_amdgcn_sched_barrier(0);
            __builtin_amdgcn_s_setprio(1);
            // swapped operands: acc regs hold 4 consecutive n at fixed m
            acc[mq + 0][nq + 0] = __builtin_amdgcn_mfma_f32_16x16x32_bf16(b00, a00, acc[mq + 0][nq + 0], 0, 0, 0);
            acc[mq + 0][nq + 0] = __builtin_amdgcn_mfma_f32_16x16x32_bf16(b01, a01, acc[mq + 0][nq + 0], 0, 0, 0);
            acc[mq + 0][nq + 1] = __builtin_amdgcn_mfma_f32_16x16x32_bf16(b10, a00, acc[mq + 0][nq + 1], 0, 0, 0);
            acc[mq + 0][nq + 1] = __builtin_amdgcn_mfma_f32_16x16x32_bf16(b11, a01, acc[mq + 0][nq + 1], 0, 0, 0);
            acc[mq + 1][nq + 0] = __builtin_amdgcn_mfma_f32_16x16x32_bf16(b00, a10, acc[mq + 1][nq + 0], 0, 0, 0);
            acc[mq + 1][nq + 0] = __builtin_amdgcn_mfma_f32_16x16x32_bf16(b01, a11, acc[mq + 1][nq + 0], 0, 0, 0);
            acc[mq + 1][nq + 1] = __builtin_amdgcn_mfma_f32_16x16x32_bf16(b10, a10, acc[mq + 1][nq + 1], 0, 0, 0);
            acc[mq + 1][nq + 1] = __builtin_amdgcn_mfma_f32_16x16x32_bf16(b11, a11, acc[mq + 1][nq + 1], 0, 0, 0);
            __builtin_amdgcn_s_setprio(0);
            __builtin_amdgcn_sched_barrier(0);
            if (p == 3) {
                // counted wait: ensure kt+1's staging done; never drain fresh loads
                if (kt < 6)       { asm volatile("s_waitcnt vmcnt(6)" ::: "memory"); }
                else if (kt == 6) { asm volatile("s_waitcnt vmcnt(0)" ::: "memory"); }
            }
            __builtin_amdgcn_s_barrier();
        }
    }
#undef STAGE_A
#undef STAGE_B

    // epilogue: acc[mi][ni] reg r -> chol[m][nb+r] (validated R2 layout)
    const float4* bt = reinterpret_cast<const float4*>(biasf);
    const float4* dt = reinterpret_cast<const float4*>(diagm);
#pragma unroll
    for (int ni = 0; ni < 4; ++ni) {
        int nb = n0 + wn + ni * 16 + lq * 4;
        float4 bv = bt[nb >> 2];
        float4 dm = dt[nb >> 2];
#pragma unroll
        for (int mi = 0; mi < 4; ++mi) {
            int m = m0 + wm + mi * 16 + lr;
            float v0 = acc[mi][ni][0] + bv.x; if (dm.x != 0.f && v0 < 0.f) v0 = 0.f;
            float v1 = acc[mi][ni][1] + bv.y; if (dm.y != 0.f && v1 < 0.f) v1 = 0.f;
            float v2 = acc[mi][ni][2] + bv.z; if (dm.z != 0.f && v2 < 0.f) v2 = 0.f;
            float v3 = acc[mi][ni][3] + bv.w; if (dm.w != 0.f && v3 < 0.f) v3 = 0.f;
            *reinterpret_cast<ushort4*>(&chol[(size_t)m * NPAD + nb]) =
                make_ushort4(f2bf(v0), f2bf(v1), f2bf(v2), f2bf(v3));
        }
    }
}

// ---------------- SYRK: out[b] = L @ L^T ----------------
__device__ __forceinline__ void lds_store_swz(unsigned short* L, int i, int j, unsigned short v) {
    int ch   = ((j >> 3) ^ i) & 7;                       // swizzled 16B chunk
    int addr = i * 128 + (ch << 4) + ((j & 7) * 2);
    *reinterpret_cast<unsigned short*>(reinterpret_cast<char*>(L) + addr) = v;
}

__global__ __launch_bounds__(256) void syrk_kernel(const unsigned short* __restrict__ chol,
                                                   float* __restrict__ out) {
    __shared__ __align__(16) unsigned short Ls[4][64 * 64];
    const int tid  = threadIdx.x;
    const int lane = tid & 63;
    const int wave = tid >> 6;

    // XCD affinity with GEMM: XCD x produced batches [1024x, 1024x+1024).
    const int bid = blockIdx.x;
    const int bb  = (bid & 7) * 256 + (bid >> 3);
    const int batch = bb * 4 + wave;
    unsigned short* L = Ls[wave];

    // Issue all chol-row loads up front (one vmcnt wait, not 17 serial)
    const unsigned int* row = reinterpret_cast<const unsigned int*>(chol + (size_t)batch * NPAD);
    unsigned int vals[17];
#pragma unroll
    for (int c = 0; c < 17; ++c) {
        int t = lane + c * 64;
        vals[c] = (t < TDIM / 2) ? row[t] : 0u;
    }

    // zero the tile (upper triangle must be 0) — wave-local LDS only
#pragma unroll
    for (int c = 0; c < 8; ++c)
        *reinterpret_cast<int4*>(reinterpret_cast<char*>(L) + (c * 64 + lane) * 16) = make_int4(0, 0, 0, 0);
    __builtin_amdgcn_sched_barrier(0);   // pin zero-writes before scatter-writes

    // scatter chol row into lower triangle
#pragma unroll
    for (int c = 0; c < 17; ++c) {
        int t = lane + c * 64;
        if (t < TDIM / 2) {
            unsigned int v = vals[c];
            int n = 2 * t;
            int i = tril_row(n);
            int j = n - i * (i + 1) / 2;
            lds_store_swz(L, i, j, (unsigned short)(v & 0xffffu));
            int i2 = i, j2 = j + 1;
            if (j2 > i2) { i2 = i + 1; j2 = 0; }
            lds_store_swz(L, i2, j2, (unsigned short)(v >> 16));
        }
    }
    // wave-local write->read ordering (no inter-wave sharing -> no s_barrier)
    asm volatile("s_waitcnt lgkmcnt(0)" ::: "memory");
    __builtin_amdgcn_sched_barrier(0);

    const int lr = lane & 15;
    const int lq = lane >> 4;
    // A and B fragments are identical reads (out = L @ L^T, B^T-form)
    bf16x8 fr[4][2];
#pragma unroll
    for (int i = 0; i < 4; ++i)
#pragma unroll
        for (int kk = 0; kk < 2; ++kk)
            fr[i][kk] = frag_load(L, i * 16 + lr, kk * 64 + lq * 16);

    f32x4 acc[4][4];
    f32x4 zero = {0.f, 0.f, 0.f, 0.f};
#pragma unroll
    for (int i = 0; i < 4; ++i)
#pragma unroll
        for (int j = 0; j < 4; ++j) acc[i][j] = zero;

#pragma unroll
    for (int mi = 0; mi < 4; ++mi)
#pragma unroll
        for (int ni = 0; ni < 4; ++ni)
#pragma unroll
            for (int kk = 0; kk < 2; ++kk)
                acc[mi][ni] = __builtin_amdgcn_mfma_f32_16x16x32_bf16(fr[mi][kk], fr[ni][kk], acc[mi][ni], 0, 0, 0);

    // out is symmetric: store acc[mi][ni] at the TRANSPOSED location so the 4
    // accumulator regs are contiguous -> 16x global_store_dwordx4
    float* ob = out + (size_t)batch * (MSZ * MSZ);
#pragma unroll
    for (int mi = 0; mi < 4; ++mi)
#pragma unroll
        for (int ni = 0; ni < 4; ++ni)
            *reinterpret_cast<f32x4*>(ob + (ni * 16 + lr) * MSZ + mi * 16 + lq * 4) = acc[mi][ni];
}

// ---------------- launch ----------------
extern "C" void kernel_launch(void* const* d_in, const int* in_sizes, int n_in,
                              void* d_out, int out_size, void* d_ws, size_t ws_size,
                              hipStream_t stream) {
    (void)in_sizes; (void)n_in; (void)out_size; (void)ws_size;
    const float* x = (const float*)d_in[0];   // [8192,512]
    const float* W = (const float*)d_in[1];   // [2080,512]
    const float* b = (const float*)d_in[2];   // [2080]
    float* out = (float*)d_out;               // [8192,64,64]

    unsigned short* xb   = (unsigned short*)d_ws;                 // 8192*512 bf16
    unsigned short* wb   = xb + (size_t)MDIM * KDIM;              // 2176*512 bf16 (padded)
    unsigned short* chol = wb + (size_t)NPAD * KDIM;              // 8192*2176 bf16
    float* biasf = (float*)(chol + (size_t)MDIM * NPAD);          // 2176 f32
    float* diagm = biasf + NPAD;                                  // 2176 f32

    int conv_blocks = (NX4 + NW4 + NT4 + 255) / 256;
    convert_kernel<<<dim3(conv_blocks), dim3(256), 0, stream>>>(x, W, b, xb, wb, biasf, diagm);
    gemm8_kernel<<<dim3(544), dim3(512), 0, stream>>>(xb, wb, biasf, diagm, chol);
    syrk_kernel<<<dim3(MDIM / 4), dim3(256), 0, stream>>>(chol, out);
}

// Round 5
// 71.078 us; speedup vs baseline: 1.1996x; 1.1996x over previous
//
#include <hip/hip_runtime.h>
#include <stdint.h>

// Problem constants
#define MDIM 8192   // batch
#define KDIM 512    // input size
#define TDIM 2080   // tril param count (64*65/2)
#define NPAD 2176   // TDIM padded to multiple of 128 (17*128)
#define MSZ  64     // matrix size
#define NSC  1040   // chol-row dwords per batch (TDIM/2)

typedef __attribute__((ext_vector_type(8))) __bf16 bf16x8;
typedef __attribute__((ext_vector_type(4))) float  f32x4;

__device__ __forceinline__ unsigned short f2bf(float f) {
    unsigned int u = __float_as_uint(f);
    u += 0x7fffu + ((u >> 16) & 1u);   // round-to-nearest-even
    return (unsigned short)(u >> 16);
}

// tril row index from linear tril index n
__device__ __forceinline__ int tril_row(int n) {
    int i = (int)((sqrtf((float)(8 * n + 1)) - 1.0f) * 0.5f);
    while ((i + 1) * (i + 2) / 2 <= n) ++i;
    while (i * (i + 1) / 2 > n) --i;
    return i;
}

// swizzled LDS byte address for L[i][j] in the [64][64] bf16 tile
__device__ __forceinline__ int swz_addr(int i, int j) {
    int ch = ((j >> 3) ^ i) & 7;                         // swizzled 16B chunk
    return i * 128 + (ch << 4) + ((j & 7) * 2);
}

// ---------------- fused convert kernel (x, W, bias/diag tables, scatter table) ----------------
#define NX4 (MDIM * KDIM / 4)        // 1048576 float4 chunks of x
#define NW4 (NPAD * KDIM / 4)        // 278528 float4 chunks of padded W
#define NT4 (NPAD / 4)               // 544 table chunks

__global__ __launch_bounds__(256) void convert_kernel(const float* __restrict__ x,
                                                      const float* __restrict__ W,
                                                      const float* __restrict__ b,
                                                      unsigned short* __restrict__ xb,
                                                      unsigned short* __restrict__ wb,
                                                      float* __restrict__ biasf,
                                                      float* __restrict__ diagm,
                                                      unsigned int* __restrict__ sidx) {
    int idx = blockIdx.x * 256 + threadIdx.x;
    if (idx < NX4) {
        float4 v = reinterpret_cast<const float4*>(x)[idx];
        reinterpret_cast<ushort4*>(xb)[idx] =
            make_ushort4(f2bf(v.x), f2bf(v.y), f2bf(v.z), f2bf(v.w));
    } else if (idx < NX4 + NW4) {
        int j = idx - NX4;
        int n = (j * 4) >> 9;                            // W row (KDIM=512)
        ushort4 o = make_ushort4(0, 0, 0, 0);
        if (n < TDIM) {
            float4 v = reinterpret_cast<const float4*>(W)[j];
            o = make_ushort4(f2bf(v.x), f2bf(v.y), f2bf(v.z), f2bf(v.w));
        }
        reinterpret_cast<ushort4*>(wb)[j] = o;
    } else if (idx < NX4 + NW4 + NT4) {
        int t = idx - NX4 - NW4;
#pragma unroll
        for (int r = 0; r < 4; ++r) {
            int n = t * 4 + r;
            float bv = 0.f, dm = 0.f;
            if (n < TDIM) {
                bv = b[n];
                int i = tril_row(n);
                dm = (n - i * (i + 1) / 2 == i) ? 1.f : 0.f;
            }
            biasf[n] = bv;
            diagm[n] = dm;
        }
    } else {
        int t = idx - NX4 - NW4 - NT4;                   // scatter-table entry (chol dword)
        if (t < NSC) {
            int n = 2 * t;
            int i = tril_row(n);
            int j = n - i * (i + 1) / 2;
            int a0 = swz_addr(i, j);
            int i2 = i, j2 = j + 1;
            if (j2 > i2) { i2 = i + 1; j2 = 0; }
            int a1 = swz_addr(i2, j2);
            sidx[t] = (unsigned int)a0 | ((unsigned int)a1 << 16);
        }
    }
}

// ---------------- shared helpers ----------------
typedef __attribute__((address_space(1))) void as1_void;
typedef __attribute__((address_space(3))) void as3_void;

__device__ __forceinline__ void gload_lds16(const void* g, void* l) {
    // 16B direct global->LDS; dest is wave-uniform base + lane*16
    __builtin_amdgcn_global_load_lds((as1_void*)(void*)g, (as3_void*)l, 16, 0, 0);
}

// LDS tiles are [rows][64] bf16 (128B rows), XOR-swizzled: byte ^= (row&7)<<4
__device__ __forceinline__ bf16x8 frag_load(const unsigned short* base, int row, int kbyte) {
    kbyte ^= (row & 7) << 4;
    return *reinterpret_cast<const bf16x8*>(reinterpret_cast<const char*>(base) + row * 128 + kbyte);
}

// ---------------- GEMM1: chol = x @ W^T + b, diag-ReLU, store bf16 (R3-proven) ----------------
// Swapped-operand MFMA (mfma(B,A)): acc regs hold 4 consecutive n at fixed m
// -> 8B chol stores, table-driven bias/ReLU (no sqrt in epilogue).
__global__ __launch_bounds__(256) void gemm_kernel(const unsigned short* __restrict__ xb,
                                                   const unsigned short* __restrict__ wb,
                                                   const float* __restrict__ biasf,
                                                   const float* __restrict__ diagm,
                                                   unsigned short* __restrict__ chol) {
    __shared__ __align__(16) unsigned short As[128 * 64];
    __shared__ __align__(16) unsigned short Bs[128 * 64];
    const int tid  = threadIdx.x;
    const int lane = tid & 63;
    const int wave = tid >> 6;

    // XCD-aware decode: grid 1088 = 8 XCDs x 136 chunks; XCD x owns m-tiles
    // [8x, 8x+8), n-fastest (A-panels + W stay resident in that XCD's L2).
    const int bid = blockIdx.x;
    const int xcd = bid & 7;
    const int c   = bid >> 3;            // 0..135
    const int mt  = xcd * 8 + c / 17;
    const int nt  = c % 17;
    const int m0 = mt * 128;
    const int n0 = nt * 128;

    const int wm = (wave >> 1) * 64;   // wave row offset in tile
    const int wn = (wave & 1) * 64;    // wave col offset in tile
    const int lr = lane & 15;
    const int lq = lane >> 4;

    f32x4 acc[4][4];
    f32x4 zero = {0.f, 0.f, 0.f, 0.f};
#pragma unroll
    for (int i = 0; i < 4; ++i)
#pragma unroll
        for (int j = 0; j < 4; ++j) acc[i][j] = zero;

    for (int k0 = 0; k0 < KDIM; k0 += 64) {
        const unsigned short* ga = xb + (size_t)m0 * KDIM + k0;
        const unsigned short* gb = wb + (size_t)n0 * KDIM + k0;
        // stage A tile: 128x64 bf16 = 1024 x 16B chunks; pre-swizzled global source
#pragma unroll
        for (int cc = 0; cc < 4; ++cc) {
            int flat = cc * 256 + tid;
            int row  = flat >> 3;
            int ch   = (flat & 7) ^ (row & 7);
            unsigned short* lb = (unsigned short*)As + (size_t)(cc * 256 + (tid & 192)) * 8;
            gload_lds16(ga + row * KDIM + ch * 8, lb);
        }
#pragma unroll
        for (int cc = 0; cc < 4; ++cc) {
            int flat = cc * 256 + tid;
            int row  = flat >> 3;
            int ch   = (flat & 7) ^ (row & 7);
            unsigned short* lb = (unsigned short*)Bs + (size_t)(cc * 256 + (tid & 192)) * 8;
            gload_lds16(gb + row * KDIM + ch * 8, lb);
        }
        __syncthreads();   // drains vmcnt -> staged data visible
#pragma unroll
        for (int kk = 0; kk < 2; ++kk) {
            bf16x8 af[4], bf[4];
            int kb = kk * 64 + lq * 16;
#pragma unroll
            for (int i = 0; i < 4; ++i) {
                af[i] = frag_load(As, wm + i * 16 + lr, kb);
                bf[i] = frag_load(Bs, wn + i * 16 + lr, kb);
            }
#pragma unroll
            for (int mi = 0; mi < 4; ++mi)
#pragma unroll
                for (int ni = 0; ni < 4; ++ni)
                    acc[mi][ni] = __builtin_amdgcn_mfma_f32_16x16x32_bf16(bf[ni], af[mi], acc[mi][ni], 0, 0, 0);
        }
        __syncthreads();   // all waves done reading before next stage overwrites
    }

    // epilogue: acc[mi][ni] reg r -> chol[m][nb+r], m = m0+wm+mi*16+lr,
    // nb = n0+wn+ni*16+lq*4 (4-aligned -> float4 table loads, ushort4 store)
    const float4* bt = reinterpret_cast<const float4*>(biasf);
    const float4* dt = reinterpret_cast<const float4*>(diagm);
#pragma unroll
    for (int ni = 0; ni < 4; ++ni) {
        int nb = n0 + wn + ni * 16 + lq * 4;
        float4 bv = bt[nb >> 2];
        float4 dm = dt[nb >> 2];
#pragma unroll
        for (int mi = 0; mi < 4; ++mi) {
            int m = m0 + wm + mi * 16 + lr;
            float v0 = acc[mi][ni][0] + bv.x; if (dm.x != 0.f && v0 < 0.f) v0 = 0.f;
            float v1 = acc[mi][ni][1] + bv.y; if (dm.y != 0.f && v1 < 0.f) v1 = 0.f;
            float v2 = acc[mi][ni][2] + bv.z; if (dm.z != 0.f && v2 < 0.f) v2 = 0.f;
            float v3 = acc[mi][ni][3] + bv.w; if (dm.w != 0.f && v3 < 0.f) v3 = 0.f;
            *reinterpret_cast<ushort4*>(&chol[(size_t)m * NPAD + nb]) =
                make_ushort4(f2bf(v0), f2bf(v1), f2bf(v2), f2bf(v3));
        }
    }
}

// ---------------- SYRK: out[b] = L @ L^T (table-driven scatter) ----------------
__global__ __launch_bounds__(256) void syrk_kernel(const unsigned short* __restrict__ chol,
                                                   const unsigned int* __restrict__ sidx,
                                                   float* __restrict__ out) {
    __shared__ __align__(16) unsigned short Ls[4][64 * 64];
    const int tid  = threadIdx.x;
    const int lane = tid & 63;
    const int wave = tid >> 6;

    // XCD affinity with GEMM: XCD x produced batches [1024x, 1024x+1024).
    const int bid = blockIdx.x;
    const int bb  = (bid & 7) * 256 + (bid >> 3);
    const int batch = bb * 4 + wave;
    unsigned short* L = Ls[wave];

    // Issue all chol-row + scatter-address loads up front (coalesced, one wait)
    const unsigned int* row = reinterpret_cast<const unsigned int*>(chol + (size_t)batch * NPAD);
    unsigned int vals[17], adr[17];
#pragma unroll
    for (int c = 0; c < 17; ++c) {
        int t = lane + c * 64;
        vals[c] = (t < NSC) ? row[t] : 0u;
        adr[c]  = (t < NSC) ? sidx[t] : 0u;
    }

    // zero the tile (upper triangle must be 0) — wave-local LDS only
#pragma unroll
    for (int c = 0; c < 8; ++c)
        *reinterpret_cast<int4*>(reinterpret_cast<char*>(L) + (c * 64 + lane) * 16) = make_int4(0, 0, 0, 0);
    __builtin_amdgcn_sched_barrier(0);   // pin zero-writes before scatter-writes

    // scatter chol row into lower triangle via precomputed swizzled addresses
#pragma unroll
    for (int c = 0; c < 17; ++c) {
        int t = lane + c * 64;
        if (t < NSC) {
            unsigned int v = vals[c];
            unsigned int a = adr[c];
            *reinterpret_cast<unsigned short*>(reinterpret_cast<char*>(L) + (a & 0xffffu)) =
                (unsigned short)(v & 0xffffu);
            *reinterpret_cast<unsigned short*>(reinterpret_cast<char*>(L) + (a >> 16)) =
                (unsigned short)(v >> 16);
        }
    }
    // wave-local write->read ordering (no inter-wave sharing -> no s_barrier)
    asm volatile("s_waitcnt lgkmcnt(0)" ::: "memory");
    __builtin_amdgcn_sched_barrier(0);

    const int lr = lane & 15;
    const int lq = lane >> 4;
    // A and B fragments are identical reads (out = L @ L^T, B^T-form)
    bf16x8 fr[4][2];
#pragma unroll
    for (int i = 0; i < 4; ++i)
#pragma unroll
        for (int kk = 0; kk < 2; ++kk)
            fr[i][kk] = frag_load(L, i * 16 + lr, kk * 64 + lq * 16);

    f32x4 acc[4][4];
    f32x4 zero = {0.f, 0.f, 0.f, 0.f};
#pragma unroll
    for (int i = 0; i < 4; ++i)
#pragma unroll
        for (int j = 0; j < 4; ++j) acc[i][j] = zero;

#pragma unroll
    for (int mi = 0; mi < 4; ++mi)
#pragma unroll
        for (int ni = 0; ni < 4; ++ni)
#pragma unroll
            for (int kk = 0; kk < 2; ++kk)
                acc[mi][ni] = __builtin_amdgcn_mfma_f32_16x16x32_bf16(fr[mi][kk], fr[ni][kk], acc[mi][ni], 0, 0, 0);

    // out is symmetric: store acc[mi][ni] at the TRANSPOSED location so the 4
    // accumulator regs are contiguous -> 16x global_store_dwordx4
    float* ob = out + (size_t)batch * (MSZ * MSZ);
#pragma unroll
    for (int mi = 0; mi < 4; ++mi)
#pragma unroll
        for (int ni = 0; ni < 4; ++ni)
            *reinterpret_cast<f32x4*>(ob + (ni * 16 + lr) * MSZ + mi * 16 + lq * 4) = acc[mi][ni];
}

// ---------------- launch ----------------
extern "C" void kernel_launch(void* const* d_in, const int* in_sizes, int n_in,
                              void* d_out, int out_size, void* d_ws, size_t ws_size,
                              hipStream_t stream) {
    (void)in_sizes; (void)n_in; (void)out_size; (void)ws_size;
    const float* x = (const float*)d_in[0];   // [8192,512]
    const float* W = (const float*)d_in[1];   // [2080,512]
    const float* b = (const float*)d_in[2];   // [2080]
    float* out = (float*)d_out;               // [8192,64,64]

    unsigned short* xb   = (unsigned short*)d_ws;                 // 8192*512 bf16
    unsigned short* wb   = xb + (size_t)MDIM * KDIM;              // 2176*512 bf16 (padded)
    unsigned short* chol = wb + (size_t)NPAD * KDIM;              // 8192*2176 bf16
    float* biasf = (float*)(chol + (size_t)MDIM * NPAD);          // 2176 f32
    float* diagm = biasf + NPAD;                                  // 2176 f32
    unsigned int* sidx = (unsigned int*)(diagm + NPAD);           // 1040 u32 scatter table

    int conv_blocks = (NX4 + NW4 + NT4 + NSC + 255) / 256;
    convert_kernel<<<dim3(conv_blocks), dim3(256), 0, stream>>>(x, W, b, xb, wb, biasf, diagm, sidx);
    gemm_kernel<<<dim3(17 * 64), dim3(256), 0, stream>>>(xb, wb, biasf, diagm, chol);
    syrk_kernel<<<dim3(MDIM / 4), dim3(256), 0, stream>>>(chol, sidx, out);
}

// Round 6
// 70.694 us; speedup vs baseline: 1.2061x; 1.0054x over previous
//
#include <hip/hip_runtime.h>
#include <stdint.h>

// Problem constants
#define MDIM 8192   // batch
#define KDIM 512    // input size
#define TDIM 2080   // tril param count (64*65/2)
#define NPAD 2176   // TDIM padded to multiple of 128 (17*128)
#define MSZ  64     // matrix size
#define NSC  1040   // chol-row dwords per batch (TDIM/2)

typedef __attribute__((ext_vector_type(8))) __bf16 bf16x8;
typedef __attribute__((ext_vector_type(4))) float  f32x4;

__device__ __forceinline__ unsigned short f2bf(float f) {
    unsigned int u = __float_as_uint(f);
    u += 0x7fffu + ((u >> 16) & 1u);   // round-to-nearest-even
    return (unsigned short)(u >> 16);
}

// tril row index from linear tril index n
__device__ __forceinline__ int tril_row(int n) {
    int i = (int)((sqrtf((float)(8 * n + 1)) - 1.0f) * 0.5f);
    while ((i + 1) * (i + 2) / 2 <= n) ++i;
    while (i * (i + 1) / 2 > n) --i;
    return i;
}

// swizzled LDS byte address for L[i][j] in the [64][64] bf16 tile
__device__ __forceinline__ int swz_addr(int i, int j) {
    int ch = ((j >> 3) ^ i) & 7;                         // swizzled 16B chunk
    return i * 128 + (ch << 4) + ((j & 7) * 2);
}

// ---------------- fused convert kernel (x, W, bias/diag tables, scatter table) ----------------
#define NX4 (MDIM * KDIM / 4)        // 1048576 float4 chunks of x
#define NW4 (NPAD * KDIM / 4)        // 278528 float4 chunks of padded W
#define NT4 (NPAD / 4)               // 544 table chunks

__global__ __launch_bounds__(256) void convert_kernel(const float* __restrict__ x,
                                                      const float* __restrict__ W,
                                                      const float* __restrict__ b,
                                                      unsigned short* __restrict__ xb,
                                                      unsigned short* __restrict__ wb,
                                                      float* __restrict__ biasf,
                                                      float* __restrict__ diagm,
                                                      unsigned int* __restrict__ sidx) {
    int idx = blockIdx.x * 256 + threadIdx.x;
    if (idx < NX4) {
        float4 v = reinterpret_cast<const float4*>(x)[idx];
        reinterpret_cast<ushort4*>(xb)[idx] =
            make_ushort4(f2bf(v.x), f2bf(v.y), f2bf(v.z), f2bf(v.w));
    } else if (idx < NX4 + NW4) {
        int j = idx - NX4;
        int n = (j * 4) >> 9;                            // W row (KDIM=512)
        ushort4 o = make_ushort4(0, 0, 0, 0);
        if (n < TDIM) {
            float4 v = reinterpret_cast<const float4*>(W)[j];
            o = make_ushort4(f2bf(v.x), f2bf(v.y), f2bf(v.z), f2bf(v.w));
        }
        reinterpret_cast<ushort4*>(wb)[j] = o;
    } else if (idx < NX4 + NW4 + NT4) {
        int t = idx - NX4 - NW4;
#pragma unroll
        for (int r = 0; r < 4; ++r) {
            int n = t * 4 + r;
            float bv = 0.f, dm = 0.f;
            if (n < TDIM) {
                bv = b[n];
                int i = tril_row(n);
                dm = (n - i * (i + 1) / 2 == i) ? 1.f : 0.f;
            }
            biasf[n] = bv;
            diagm[n] = dm;
        }
    } else {
        int t = idx - NX4 - NW4 - NT4;                   // scatter-table entry (chol dword)
        if (t < NSC) {
            int n = 2 * t;
            int i = tril_row(n);
            int j = n - i * (i + 1) / 2;
            int a0 = swz_addr(i, j);
            int i2 = i, j2 = j + 1;
            if (j2 > i2) { i2 = i + 1; j2 = 0; }
            int a1 = swz_addr(i2, j2);
            sidx[t] = (unsigned int)a0 | ((unsigned int)a1 << 16);
        }
    }
}

// ---------------- shared helpers ----------------
typedef __attribute__((address_space(1))) void as1_void;
typedef __attribute__((address_space(3))) void as3_void;

__device__ __forceinline__ void gload_lds16(const void* g, void* l) {
    // 16B direct global->LDS; dest is wave-uniform base + lane*16
    __builtin_amdgcn_global_load_lds((as1_void*)(void*)g, (as3_void*)l, 16, 0, 0);
}

// LDS tiles are [rows][64] bf16 (128B rows), XOR-swizzled: byte ^= (row&7)<<4
__device__ __forceinline__ bf16x8 frag_load(const unsigned short* base, int row, int kbyte) {
    kbyte ^= (row & 7) << 4;
    return *reinterpret_cast<const bf16x8*>(reinterpret_cast<const char*>(base) + row * 128 + kbyte);
}

// ---------------- GEMM1: chol = x @ W^T + b, diag-ReLU, store bf16 ----------------
// Swapped-operand MFMA (mfma(B,A)): acc regs hold 4 consecutive n at fixed m
// -> 8B chol stores, table-driven bias/ReLU (no sqrt in epilogue).
// __launch_bounds__(256, 4): cap VGPR at 128 -> 4 blocks/CU (was ~164 VGPR ->
// 3 blocks/CU). The 2-barrier structure's latency hiding comes from co-resident
// blocks (m114); +1 block/CU = +33% overlap capacity.
__global__ __launch_bounds__(256, 4) void gemm_kernel(const unsigned short* __restrict__ xb,
                                                      const unsigned short* __restrict__ wb,
                                                      const float* __restrict__ biasf,
                                                      const float* __restrict__ diagm,
                                                      unsigned short* __restrict__ chol) {
    __shared__ __align__(16) unsigned short As[128 * 64];
    __shared__ __align__(16) unsigned short Bs[128 * 64];
    const int tid  = threadIdx.x;
    const int lane = tid & 63;
    const int wave = tid >> 6;

    // XCD-aware decode: grid 1088 = 8 XCDs x 136 chunks; XCD x owns m-tiles
    // [8x, 8x+8), n-fastest (A-panels + W stay resident in that XCD's L2).
    const int bid = blockIdx.x;
    const int xcd = bid & 7;
    const int c   = bid >> 3;            // 0..135
    const int mt  = xcd * 8 + c / 17;
    const int nt  = c % 17;
    const int m0 = mt * 128;
    const int n0 = nt * 128;

    const int wm = (wave >> 1) * 64;   // wave row offset in tile
    const int wn = (wave & 1) * 64;    // wave col offset in tile
    const int lr = lane & 15;
    const int lq = lane >> 4;

    f32x4 acc[4][4];
    f32x4 zero = {0.f, 0.f, 0.f, 0.f};
#pragma unroll
    for (int i = 0; i < 4; ++i)
#pragma unroll
        for (int j = 0; j < 4; ++j) acc[i][j] = zero;

    for (int k0 = 0; k0 < KDIM; k0 += 64) {
        const unsigned short* ga = xb + (size_t)m0 * KDIM + k0;
        const unsigned short* gb = wb + (size_t)n0 * KDIM + k0;
        // stage A tile: 128x64 bf16 = 1024 x 16B chunks; pre-swizzled global source
#pragma unroll
        for (int cc = 0; cc < 4; ++cc) {
            int flat = cc * 256 + tid;
            int row  = flat >> 3;
            int ch   = (flat & 7) ^ (row & 7);
            unsigned short* lb = (unsigned short*)As + (size_t)(cc * 256 + (tid & 192)) * 8;
            gload_lds16(ga + row * KDIM + ch * 8, lb);
        }
#pragma unroll
        for (int cc = 0; cc < 4; ++cc) {
            int flat = cc * 256 + tid;
            int row  = flat >> 3;
            int ch   = (flat & 7) ^ (row & 7);
            unsigned short* lb = (unsigned short*)Bs + (size_t)(cc * 256 + (tid & 192)) * 8;
            gload_lds16(gb + row * KDIM + ch * 8, lb);
        }
        __syncthreads();   // drains vmcnt -> staged data visible
#pragma unroll
        for (int kk = 0; kk < 2; ++kk) {
            bf16x8 af[4], bf[4];
            int kb = kk * 64 + lq * 16;
#pragma unroll
            for (int i = 0; i < 4; ++i) {
                af[i] = frag_load(As, wm + i * 16 + lr, kb);
                bf[i] = frag_load(Bs, wn + i * 16 + lr, kb);
            }
#pragma unroll
            for (int mi = 0; mi < 4; ++mi)
#pragma unroll
                for (int ni = 0; ni < 4; ++ni)
                    acc[mi][ni] = __builtin_amdgcn_mfma_f32_16x16x32_bf16(bf[ni], af[mi], acc[mi][ni], 0, 0, 0);
        }
        __syncthreads();   // all waves done reading before next stage overwrites
    }

    // epilogue: acc[mi][ni] reg r -> chol[m][nb+r], m = m0+wm+mi*16+lr,
    // nb = n0+wn+ni*16+lq*4 (4-aligned -> float4 table loads, ushort4 store)
    const float4* bt = reinterpret_cast<const float4*>(biasf);
    const float4* dt = reinterpret_cast<const float4*>(diagm);
#pragma unroll
    for (int ni = 0; ni < 4; ++ni) {
        int nb = n0 + wn + ni * 16 + lq * 4;
        float4 bv = bt[nb >> 2];
        float4 dm = dt[nb >> 2];
#pragma unroll
        for (int mi = 0; mi < 4; ++mi) {
            int m = m0 + wm + mi * 16 + lr;
            float v0 = acc[mi][ni][0] + bv.x; if (dm.x != 0.f && v0 < 0.f) v0 = 0.f;
            float v1 = acc[mi][ni][1] + bv.y; if (dm.y != 0.f && v1 < 0.f) v1 = 0.f;
            float v2 = acc[mi][ni][2] + bv.z; if (dm.z != 0.f && v2 < 0.f) v2 = 0.f;
            float v3 = acc[mi][ni][3] + bv.w; if (dm.w != 0.f && v3 < 0.f) v3 = 0.f;
            *reinterpret_cast<ushort4*>(&chol[(size_t)m * NPAD + nb]) =
                make_ushort4(f2bf(v0), f2bf(v1), f2bf(v2), f2bf(v3));
        }
    }
}

// ---------------- SYRK: out[b] = L @ L^T (table-driven scatter) ----------------
__global__ __launch_bounds__(256) void syrk_kernel(const unsigned short* __restrict__ chol,
                                                   const unsigned int* __restrict__ sidx,
                                                   float* __restrict__ out) {
    __shared__ __align__(16) unsigned short Ls[4][64 * 64];
    const int tid  = threadIdx.x;
    const int lane = tid & 63;
    const int wave = tid >> 6;

    // XCD affinity with GEMM: XCD x produced batches [1024x, 1024x+1024).
    const int bid = blockIdx.x;
    const int bb  = (bid & 7) * 256 + (bid >> 3);
    const int batch = bb * 4 + wave;
    unsigned short* L = Ls[wave];

    // Issue all chol-row + scatter-address loads up front (coalesced, one wait)
    const unsigned int* row = reinterpret_cast<const unsigned int*>(chol + (size_t)batch * NPAD);
    unsigned int vals[17], adr[17];
#pragma unroll
    for (int c = 0; c < 17; ++c) {
        int t = lane + c * 64;
        vals[c] = (t < NSC) ? row[t] : 0u;
        adr[c]  = (t < NSC) ? sidx[t] : 0u;
    }

    // zero the tile (upper triangle must be 0) — wave-local LDS only
#pragma unroll
    for (int c = 0; c < 8; ++c)
        *reinterpret_cast<int4*>(reinterpret_cast<char*>(L) + (c * 64 + lane) * 16) = make_int4(0, 0, 0, 0);
    __builtin_amdgcn_sched_barrier(0);   // pin zero-writes before scatter-writes

    // scatter chol row into lower triangle via precomputed swizzled addresses
#pragma unroll
    for (int c = 0; c < 17; ++c) {
        int t = lane + c * 64;
        if (t < NSC) {
            unsigned int v = vals[c];
            unsigned int a = adr[c];
            *reinterpret_cast<unsigned short*>(reinterpret_cast<char*>(L) + (a & 0xffffu)) =
                (unsigned short)(v & 0xffffu);
            *reinterpret_cast<unsigned short*>(reinterpret_cast<char*>(L) + (a >> 16)) =
                (unsigned short)(v >> 16);
        }
    }
    // wave-local write->read ordering (no inter-wave sharing -> no s_barrier)
    asm volatile("s_waitcnt lgkmcnt(0)" ::: "memory");
    __builtin_amdgcn_sched_barrier(0);

    const int lr = lane & 15;
    const int lq = lane >> 4;
    // A and B fragments are identical reads (out = L @ L^T, B^T-form)
    bf16x8 fr[4][2];
#pragma unroll
    for (int i = 0; i < 4; ++i)
#pragma unroll
        for (int kk = 0; kk < 2; ++kk)
            fr[i][kk] = frag_load(L, i * 16 + lr, kk * 64 + lq * 16);

    f32x4 acc[4][4];
    f32x4 zero = {0.f, 0.f, 0.f, 0.f};
#pragma unroll
    for (int i = 0; i < 4; ++i)
#pragma unroll
        for (int j = 0; j < 4; ++j) acc[i][j] = zero;

#pragma unroll
    for (int mi = 0; mi < 4; ++mi)
#pragma unroll
        for (int ni = 0; ni < 4; ++ni)
#pragma unroll
            for (int kk = 0; kk < 2; ++kk)
                acc[mi][ni] = __builtin_amdgcn_mfma_f32_16x16x32_bf16(fr[mi][kk], fr[ni][kk], acc[mi][ni], 0, 0, 0);

    // out is symmetric: store acc[mi][ni] at the TRANSPOSED location so the 4
    // accumulator regs are contiguous -> 16x global_store_dwordx4
    float* ob = out + (size_t)batch * (MSZ * MSZ);
#pragma unroll
    for (int mi = 0; mi < 4; ++mi)
#pragma unroll
        for (int ni = 0; ni < 4; ++ni)
            *reinterpret_cast<f32x4*>(ob + (ni * 16 + lr) * MSZ + mi * 16 + lq * 4) = acc[mi][ni];
}

// ---------------- launch ----------------
extern "C" void kernel_launch(void* const* d_in, const int* in_sizes, int n_in,
                              void* d_out, int out_size, void* d_ws, size_t ws_size,
                              hipStream_t stream) {
    (void)in_sizes; (void)n_in; (void)out_size; (void)ws_size;
    const float* x = (const float*)d_in[0];   // [8192,512]
    const float* W = (const float*)d_in[1];   // [2080,512]
    const float* b = (const float*)d_in[2];   // [2080]
    float* out = (float*)d_out;               // [8192,64,64]

    unsigned short* xb   = (unsigned short*)d_ws;                 // 8192*512 bf16
    unsigned short* wb   = xb + (size_t)MDIM * KDIM;              // 2176*512 bf16 (padded)
    unsigned short* chol = wb + (size_t)NPAD * KDIM;              // 8192*2176 bf16
    float* biasf = (float*)(chol + (size_t)MDIM * NPAD);          // 2176 f32
    float* diagm = biasf + NPAD;                                  // 2176 f32
    unsigned int* sidx = (unsigned int*)(diagm + NPAD);           // 1040 u32 scatter table

    int conv_blocks = (NX4 + NW4 + NT4 + NSC + 255) / 256;
    convert_kernel<<<dim3(conv_blocks), dim3(256), 0, stream>>>(x, W, b, xb, wb, biasf, diagm, sidx);
    gemm_kernel<<<dim3(17 * 64), dim3(256), 0, stream>>>(xb, wb, biasf, diagm, chol);
    syrk_kernel<<<dim3(MDIM / 4), dim3(256), 0, stream>>>(chol, sidx, out);
}